// Round 23
// baseline (167.447 us; speedup 1.0000x reference)
//
#include <hip/hip_runtime.h>
#include <hip/hip_bf16.h>

#define B    16
#define NA   25200
#define NCH  85
#define NCLS 80
#define K    2048
#define CAP  4096
#define ACAP 4096
#define DET  300
#define TILE 64
#define NTILES 394                     // ceil(25200/64)
#define PBLK 64                        // k_pairs blocks per image
#define LBUF 2304                      // k_pairs LDS buffer
#define SBASE  0x3FD0000000000000ULL   // bits of 0.25 (double)
#define SSHIFT 42                      // -> 2048 bins over (0.25, 1.0)

typedef unsigned long long u64;
typedef unsigned int u32;
typedef unsigned short u16;
typedef unsigned char u8;

__device__ __forceinline__ double dsig(float x) { return 1.0 / (1.0 + exp(-(double)x)); }
__device__ __forceinline__ float  fsig(float x) { return 1.0f / (1.0f + __expf(-x)); }

// ---- Pass 1: full sweep with register-prefetch double buffering. ----
__global__ void __launch_bounds__(256) k_hist(const float* __restrict__ head,
                                              u32* __restrict__ phist, u16* __restrict__ smax16) {
    __shared__ float rows[TILE * NCH];
    __shared__ int h[2048];
    __shared__ float smaxT[TILE][4];
    int tid = threadIdx.x;
    int hblk = gridDim.x;
    for (int i = tid; i < 2048; i += 256) h[i] = 0;
    int img = blockIdx.y;
    const float* ibase = head + (size_t)img * NA * NCH;

    float4 pf[6];
    int tile = blockIdx.x;
    {
        int a0 = tile * TILE;
        int na = NA - a0; if (na > TILE) na = TILE;
        int nf4 = (na * NCH) >> 2;
        const float4* src = (const float4*)(ibase + (size_t)a0 * NCH);
        #pragma unroll
        for (int u = 0; u < 6; ++u) { int i = tid + u * 256; pf[u] = (i < nf4) ? src[i] : make_float4(0.f,0.f,0.f,0.f); }
    }
    for (; tile < NTILES; tile += hblk) {
        int a0 = tile * TILE;
        int na = NA - a0; if (na > TILE) na = TILE;
        int nf4 = (na * NCH) >> 2;
        __syncthreads();
        #pragma unroll
        for (int u = 0; u < 6; ++u) { int i = tid + u * 256; if (i < nf4) ((float4*)rows)[i] = pf[u]; }
        __syncthreads();
        int nt = tile + hblk;
        if (nt < NTILES) {
            int a0n = nt * TILE;
            int nan_ = NA - a0n; if (nan_ > TILE) nan_ = TILE;
            int nf4n = (nan_ * NCH) >> 2;
            const float4* srcn = (const float4*)(ibase + (size_t)a0n * NCH);
            #pragma unroll
            for (int u = 0; u < 6; ++u) { int i = tid + u * 256; pf[u] = (i < nf4n) ? srcn[i] : make_float4(0.f,0.f,0.f,0.f); }
        }
        for (int t = tid; t < 4 * na; t += 256) {
            int a = t >> 2, q = t & 3;
            float fo = fsig(rows[a * NCH + 4]);
            float lm = 0.0f;
            if (fo > 0.25f) {
                float qq = 0.24975f / fo;
                float cth = __logf(qq) - __logf(1.0f - qq);
                int c0 = q * 20;
                for (int c = c0; c < c0 + 20; ++c) {
                    float cl = rows[a * NCH + 5 + c];
                    if (cl > cth) {
                        float sc = fo * fsig(cl);
                        lm = fmaxf(lm, sc);
                        if (sc > 0.25f) {
                            u64 bits = (u64)__double_as_longlong((double)sc);
                            int bb = (int)((bits - SBASE) >> SSHIFT);
                            if (bb > 2047) bb = 2047;
                            atomicAdd(&h[bb], 1);
                        }
                    }
                }
            }
            smaxT[a][q] = lm;
        }
        __syncthreads();
        for (int t = tid; t < na; t += 256) {
            float m = fmaxf(fmaxf(smaxT[t][0], smaxT[t][1]), fmaxf(smaxT[t][2], smaxT[t][3]));
            u32 mb = __float_as_uint(m);
            smax16[(size_t)img * NA + a0 + t] = (u16)((mb + 0xFFFFu) >> 16);  // round UP
        }
    }
    __syncthreads();
    u32* dst = phist + ((size_t)img * hblk + blockIdx.x) * 2048;
    for (int i = tid; i < 2048; i += 256) dst[i] = (u32)h[i];
}

// ---- Pass 2a: parallel partial-histogram reduce (+ cnt/cntA zeroing) ----
__global__ void __launch_bounds__(256) k_redsum(const u32* __restrict__ phist,
                                                int* __restrict__ hist, int hblk,
                                                u32* __restrict__ cnt, u32* __restrict__ cntA) {
    int img = blockIdx.x;
    int bin = blockIdx.y * 256 + threadIdx.x;
    if (blockIdx.y == 0 && threadIdx.x == 0) cnt[img] = 0;
    if (blockIdx.y == 0 && threadIdx.x == 1) cntA[img] = 0;
    const u32* base = phist + (size_t)img * hblk * 2048 + bin;
    u32 s = 0;
    int p = 0;
    for (; p + 4 <= hblk; p += 4) {
        u32 a0 = base[(size_t)(p + 0) * 2048];
        u32 a1 = base[(size_t)(p + 1) * 2048];
        u32 a2 = base[(size_t)(p + 2) * 2048];
        u32 a3 = base[(size_t)(p + 3) * 2048];
        s += a0 + a1 + a2 + a3;
    }
    for (; p < hblk; ++p) s += base[(size_t)p * 2048];
    hist[img * 2048 + bin] = (int)s;
}

// ---- Pass 2b: cut-bin search, one wave per image ----
__global__ void __launch_bounds__(1024) k_cut(const int* __restrict__ hist, u64* __restrict__ cut) {
    int lane = threadIdx.x & 63;
    int img  = threadIdx.x >> 6;
    const int* h = hist + img * 2048;
    int v[32];
    #pragma unroll
    for (int ch = 0; ch < 32; ++ch) v[ch] = h[2047 - ch * 64 - lane];
    int cum = 0; u64 cb = 0;
    #pragma unroll
    for (int ch = 0; ch < 32; ++ch) {
        int pfx = v[ch];
        for (int d = 1; d < 64; d <<= 1) { int o = __shfl_up(pfx, d, 64); if (lane >= d) pfx += o; }
        u64 ball = __ballot(cum + pfx >= K);
        if (ball) {
            int fl = __ffsll((long long)ball) - 1;
            int bin = 2047 - ch * 64 - fl;
            cb = (bin >= 1) ? (SBASE + ((u64)(bin - 1) << SSHIFT)) : 0ULL;
            break;
        }
        cum += __shfl(pfx, 63, 64);
    }
    if (lane == 0) cut[img] = cb;
}

// ---- Pass 3a: screen anchors by smax upper bound ----
__global__ void __launch_bounds__(256) k_screen(const u16* __restrict__ smax16, const u64* __restrict__ cut,
                                                u32* __restrict__ cntA, int* __restrict__ alist) {
    __shared__ int lcnt, lbase, buf[256];
    int img = blockIdx.y;
    int a = blockIdx.x * 256 + threadIdx.x;
    if (threadIdx.x == 0) lcnt = 0;
    __syncthreads();
    u64 cutb = cut[img];
    float cutf = cutb ? (float)__longlong_as_double((long long)cutb) : 0.25f;
    float pre = fmaxf(0.2489f, cutf * 0.999f);
    if (a < NA) {
        float fup = __uint_as_float(((u32)smax16[(size_t)img * NA + a]) << 16);
        if (fup >= pre) buf[atomicAdd(&lcnt, 1)] = a;
    }
    __syncthreads();
    if (threadIdx.x == 0 && lcnt) lbase = atomicAdd(&cntA[img], (u32)lcnt);
    __syncthreads();
    for (int i = threadIdx.x; i < lcnt; i += 256) {
        int pos = lbase + i;
        if (pos < ACAP) alist[img * ACAP + pos] = buf[i];
    }
}

// ---- Pass 3b: pairs with per-block LDS compaction + f64 box decode at flush ----
__global__ void __launch_bounds__(256) k_pairs(const float* __restrict__ head, const u64* __restrict__ cut,
                                               const float* __restrict__ grid, const float* __restrict__ ag,
                                               const float* __restrict__ stv,
                                               const u32* __restrict__ cntA, const int* __restrict__ alist,
                                               u32* __restrict__ cnt, u64* __restrict__ sb, u32* __restrict__ si,
                                               double* __restrict__ boxg) {
    __shared__ u64 lsb[LBUF];
    __shared__ u32 lsi[LBUF];
    __shared__ u32 lcnt, lbase;
    int img = blockIdx.y;
    int tid = threadIdx.x;
    u64 cutb = cut[img];
    float cutf = cutb ? (float)__longlong_as_double((long long)cutb) : 0.25f;
    float pre = fmaxf(0.2489f, cutf * 0.999f);
    int nsur = (int)cntA[img]; if (nsur > ACAP) nsur = ACAP;
    int npairs = nsur * NCLS;
    u64* sbi = sb + (size_t)img * CAP;
    u32* sii = si + (size_t)img * CAP;
    const float* ibase = head + (size_t)img * NA * NCH;
    if (tid == 0) lcnt = 0;
    __syncthreads();

    int base = blockIdx.x * 256;
    int ntrip = (npairs > base) ? (npairs - base + PBLK * 256 - 1) / (PBLK * 256) : 0;
    for (int t = 0; t <= ntrip; ++t) {          // extra trip = final flush
        if (t < ntrip) {
            int p = base + tid + t * PBLK * 256;
            if (p < npairs) {
                int ai = (int)((u32)p / NCLS);
                int c  = p - ai * NCLS;
                int a  = alist[img * ACAP + ai];
                const float* row = ibase + (size_t)a * NCH;
                float o = row[4], cl = row[5 + c];
                float s32 = fsig(o) * fsig(cl);
                if (s32 >= pre) {
                    double sc = dsig(o) * dsig(cl);        // exact f64 decision
                    if (sc > 0.25) {
                        u64 bits = (u64)__double_as_longlong(sc);
                        if (bits >= cutb) {
                            u32 pos = atomicAdd(&lcnt, 1u);
                            if (pos < LBUF) { lsb[pos] = bits; lsi[pos] = (u32)(a * NCLS + c); }
                        }
                    }
                }
            }
        }
        __syncthreads();
        bool last = (t == ntrip);
        if ((!last && lcnt >= 2048) || (last && lcnt > 0)) {
            u32 n = lcnt; if (n > LBUF) n = LBUF;
            if (tid == 0) lbase = atomicAdd(&cnt[img], n);
            __syncthreads();
            for (u32 i = tid; i < n; i += 256) {
                u32 pos = lbase + i;
                if (pos < CAP) {
                    u32 idx = lsi[i];
                    sbi[pos] = lsb[i]; sii[pos] = idx;
                    int a = (int)(idx / NCLS);
                    const float* row = ibase + (size_t)a * NCH;
                    double p0 = dsig(row[0]), p1 = dsig(row[1]), p2 = dsig(row[2]), p3 = dsig(row[3]);
                    double st = (double)stv[a];
                    double xc = (p0 * 2.0 - 0.5 + (double)grid[a * 2 + 0]) * st;
                    double yc = (p1 * 2.0 - 0.5 + (double)grid[a * 2 + 1]) * st;
                    double w = p2 * 2.0; w = (w * w) * (double)ag[a * 2 + 0];
                    double h = p3 * 2.0; h = (h * h) * (double)ag[a * 2 + 1];
                    double* bg = boxg + ((size_t)img * CAP + pos) * 4;
                    bg[0] = xc - w * 0.5; bg[1] = yc - h * 0.5;
                    bg[2] = xc + w * 0.5; bg[3] = yc + h * 0.5;
                }
            }
            __syncthreads();
            if (tid == 0) lcnt = 0;
            __syncthreads();
        }
    }
}

// ---- Pass 4a: counting sort -> sorted sb/si + permg + keptg=1; ALSO builds
// seg/clsbase/offb (verbatim front-half algorithm on the in-LDS sorted data)
// and the |dclass|>=2 viol precheck -> global segg/clsbg/offbg/violg. ----
__global__ void __launch_bounds__(1024) k_sortp(const u32* __restrict__ cntArr,
                                                u64* __restrict__ sb, u32* __restrict__ si,
                                                u16* __restrict__ permg, u8* __restrict__ keptg,
                                                int* __restrict__ violg,
                                                const double* __restrict__ boxg,
                                                u16* __restrict__ segg, int* __restrict__ clsbg,
                                                double* __restrict__ offbg) {
    __shared__ u64 TA[4096];
    __shared__ u32 TI[4096];
    __shared__ u16 TP[4096];
    __shared__ u32 h2[2048];
    __shared__ u32 cntb[2048];
    __shared__ u32 segtot[32];
    __shared__ u32 chunkcnt[32][NCLS];
    __shared__ int clsbase[NCLS + 1];
    __shared__ int clscnt[NCLS];
    __shared__ double redA[16], redB[16];
    int img = blockIdx.x;
    int tid = threadIdx.x;
    int lane = tid & 63, wv = tid >> 6;
    u32* tmp = TI;

    u64* A = sb + (size_t)img * CAP;
    u32* I = si + (size_t)img * CAP;
    int cnt = (int)cntArr[img]; if (cnt > CAP) cnt = CAP;

    keptg[(size_t)img * 2048 + tid] = 1;
    keptg[(size_t)img * 2048 + 1024 + tid] = 1;
    if (tid == 0) violg[img] = 0;

    for (int b = tid; b < 2048; b += 1024) h2[b] = 0;
    __syncthreads();
    for (int e = tid; e < cnt; e += 1024) {
        u64 bits = A[e];
        int b = (int)((bits - SBASE) >> SSHIFT);
        b = b < 0 ? 0 : (b > 2047 ? 2047 : b);
        atomicAdd(&h2[b], 1u);
    }
    __syncthreads();
    for (int s = wv; s < 32; s += 16) {
        int r = s * 64 + lane;
        u32 v = h2[2047 - r];
        cntb[2047 - r] = v;
        u32 p = v;
        for (int d = 1; d < 64; d <<= 1) { u32 o = __shfl_up(p, d, 64); if (lane >= d) p += o; }
        if (lane == 63) segtot[s] = p;
        tmp[r] = p - v;
    }
    __syncthreads();
    if (tid < 32) {
        u32 v = segtot[tid], p = v;
        for (int d = 1; d < 32; d <<= 1) { u32 o = __shfl_up(p, d, 64); if (lane >= d) p += o; }
        segtot[tid] = p - v;
    }
    __syncthreads();
    for (int s = wv; s < 32; s += 16) {
        int r = s * 64 + lane;
        h2[2047 - r] = tmp[r] + segtot[s];
    }
    __syncthreads();
    for (int e = tid; e < 4096; e += 1024) if (e >= cnt) { TA[e] = 0ULL; TI[e] = 0xFFFFFFFFu; TP[e] = 0; }
    __syncthreads();
    for (int e = tid; e < cnt; e += 1024) {
        u64 bits = A[e]; u32 idx = I[e];
        int b = (int)((bits - SBASE) >> SSHIFT);
        b = b < 0 ? 0 : (b > 2047 ? 2047 : b);
        u32 slot = atomicAdd(&h2[b], 1u);
        if (slot < 4096u) { TA[slot] = bits; TI[slot] = idx; TP[slot] = (u16)e; }
    }
    __syncthreads();
    u64 rb[4]; u32 ri[4]; int rp[4]; u16 rq[4];
    #pragma unroll
    for (int s4 = 0; s4 < 4; ++s4) {
        int p = tid + s4 * 1024;
        rp[s4] = -1;
        if (p < cnt) {
            u64 kb = TA[p]; u32 ki = TI[p]; u16 kq = TP[p];
            int b = (int)((kb - SBASE) >> SSHIFT);
            b = b < 0 ? 0 : (b > 2047 ? 2047 : b);
            int en = (int)h2[b];
            int st = en - (int)cntb[b];
            int r = st;
            for (int j = st; j < en; ++j) {
                u64 b2 = TA[j]; u32 i2 = TI[j];
                if (b2 > kb || (b2 == kb && i2 < ki)) ++r;
            }
            rb[s4] = kb; ri[s4] = ki; rq[s4] = kq; rp[s4] = r;
        }
    }
    __syncthreads();
    #pragma unroll
    for (int s4 = 0; s4 < 4; ++s4)
        if (rp[s4] >= 0 && rp[s4] < 4096) { TA[rp[s4]] = rb[s4]; TI[rp[s4]] = ri[s4]; TP[rp[s4]] = rq[s4]; }
    __syncthreads();
    A[tid] = TA[tid];               I[tid] = TI[tid];
    A[1024 + tid] = TA[1024 + tid]; I[1024 + tid] = TI[1024 + tid];
    permg[(size_t)img * 2048 + tid]        = TP[tid];
    permg[(size_t)img * 2048 + 1024 + tid] = TP[1024 + tid];

    // ---- build seg/clsbase/offb/precheck (moved here from downstream) ----
    if (tid < NCLS) clscnt[tid] = 0;
    for (int i = tid; i < 32 * NCLS; i += 1024) ((u32*)chunkcnt)[i] = 0;
    __syncthreads();
    int lab_[2]; bool val_[2];
    double lmax = -1e300, lmin = 1e300;
    #pragma unroll
    for (int q = 0; q < 2; ++q) {
        int slot = q * 1024 + tid;
        val_[q] = (TA[slot] != 0ULL);
        lab_[q] = 0;
        if (val_[q]) {
            lab_[q] = (int)(TI[slot] % NCLS);
            const double* bg = boxg + ((size_t)img * CAP + TP[slot]) * 4;
            double b0 = bg[0], b1 = bg[1], b2 = bg[2], b3 = bg[3];
            lmax = fmax(lmax, fmax(fmax(b0, b1), fmax(b2, b3)));
            lmin = fmin(lmin, fmin(fmin(b0, b1), fmin(b2, b3)));
            atomicAdd(&clscnt[lab_[q]], 1);
            atomicAdd(&chunkcnt[slot >> 6][lab_[q]], 1u);
        }
    }
    for (int d = 1; d < 64; d <<= 1) {
        lmax = fmax(lmax, __shfl_xor(lmax, d, 64));
        lmin = fmin(lmin, __shfl_xor(lmin, d, 64));
    }
    if (lane == 0) { redA[wv] = lmax; redB[wv] = lmin; }
    __syncthreads();
    if (tid == 0) {
        double m_ = redA[0], mn = redB[0];
        for (int w2 = 1; w2 < 16; ++w2) { m_ = fmax(m_, redA[w2]); mn = fmin(mn, redB[w2]); }
        offbg[img] = m_ + 1.0;
        if (m_ + 2.0 + mn < 0.0) atomicOr(&violg[img], 1);   // |dclass|>=2 possible
    }
    __syncthreads();
    if (tid < 64) {
        int c0 = clscnt[lane];
        int c1 = (lane < NCLS - 64) ? clscnt[64 + lane] : 0;
        int p0 = c0;
        for (int d = 1; d < 64; d <<= 1) { int o = __shfl_up(p0, d, 64); if (lane >= d) p0 += o; }
        int tot0 = __shfl(p0, 63, 64);
        int p1 = c1;
        for (int d = 1; d < 64; d <<= 1) { int o = __shfl_up(p1, d, 64); if (lane >= d) p1 += o; }
        clsbase[lane] = p0 - c0;
        if (lane < NCLS - 64) clsbase[64 + lane] = tot0 + p1 - c1;
        if (lane == 63) clsbase[NCLS] = tot0 + __shfl(p1, NCLS - 64 - 1, 64);
    }
    __syncthreads();
    if (tid < NCLS) {
        int running = clsbase[tid];
        for (int ch = 0; ch < 32; ++ch) {
            u32 t = chunkcnt[ch][tid];
            chunkcnt[ch][tid] = (u32)running;
            running += (int)t;
        }
    }
    for (int i = tid; i <= NCLS; i += 1024) clsbg[img * 81 + i] = clsbase[i];
    __syncthreads();
    #pragma unroll
    for (int q = 0; q < 2; ++q) {
        int cl = val_[q] ? lab_[q] : -1;
        int rank = 0;
        for (int d = 1; d < 64; ++d) {
            int oc = __shfl_up(cl, d, 64);
            if (lane >= d && oc == cl) ++rank;
        }
        if (val_[q]) {
            int slot = q * 1024 + tid;
            segg[(size_t)img * 2048 + chunkcnt[slot >> 6][cl] + rank] = (u16)slot;
        }
    }
}

// ==== front-half macro (used ONLY by k_fin's cold path) ====
#define NMS_FRONT_HALF                                                          \
    u64 sv[2]; u32 fidx[2];                                                     \
    sv[0] = A[tid];        fidx[0] = I[tid];                                    \
    sv[1] = A[1024 + tid]; fidx[1] = I[1024 + tid];                             \
    if (tid < NCLS) clscnt[tid] = 0;                                            \
    for (int i = tid; i < 32 * NCLS; i += 1024) ((u32*)chunkcnt)[i] = 0;        \
    double bx[2][4];                                                            \
    int lab[2];                                                                 \
    bool val[2];                                                                \
    double lmax = -1e300, lmin = 1e300;                                         \
    __syncthreads();                                                            \
    _Pragma("unroll")                                                           \
    for (int q = 0; q < 2; ++q) {                                               \
        int slot = q * 1024 + tid;                                              \
        val[q] = (sv[q] != 0ULL);                                               \
        bx[q][0] = bx[q][1] = bx[q][2] = bx[q][3] = 0.0;                        \
        lab[q] = 0;                                                             \
        if (val[q]) {                                                           \
            lab[q] = (int)(fidx[q] % NCLS);                                     \
            int p = (int)permg[(size_t)img * 2048 + slot];                      \
            const double* bg = boxg + ((size_t)img * CAP + p) * 4;              \
            bx[q][0] = bg[0]; bx[q][1] = bg[1];                                 \
            bx[q][2] = bg[2]; bx[q][3] = bg[3];                                 \
            lmax = fmax(lmax, fmax(fmax(bx[q][0], bx[q][1]), fmax(bx[q][2], bx[q][3]))); \
            lmin = fmin(lmin, fmin(fmin(bx[q][0], bx[q][1]), fmin(bx[q][2], bx[q][3]))); \
            atomicAdd(&clscnt[lab[q]], 1);                                      \
            atomicAdd(&chunkcnt[slot >> 6][lab[q]], 1u);                        \
        }                                                                       \
        labs[slot] = val[q] ? (u16)lab[q] : (u16)0xFFFF;                        \
    }                                                                           \
    for (int d = 1; d < 64; d <<= 1) {                                          \
        lmax = fmax(lmax, __shfl_xor(lmax, d, 64));                             \
        lmin = fmin(lmin, __shfl_xor(lmin, d, 64));                             \
    }                                                                           \
    if (lane == 0) { red[wv] = lmax; red2[wv] = lmin; }                         \
    __syncthreads();                                                            \
    if (tid == 0) {                                                             \
        double m = red[0], mn = red2[0];                                        \
        for (int w2 = 1; w2 < 16; ++w2) { m = fmax(m, red[w2]); mn = fmin(mn, red2[w2]); } \
        s_offb = m + 1.0;                                                       \
        s_viol2 = (m + 2.0 + mn < 0.0) ? 1 : 0;                                 \
    }                                                                           \
    __syncthreads();                                                            \
    double offb = s_offb;                                                       \
    double oB[2][4], aR[2];                                                     \
    _Pragma("unroll")                                                           \
    for (int q = 0; q < 2; ++q) {                                               \
        double off = offb * (double)lab[q];                                     \
        oB[q][0] = bx[q][0] + off; oB[q][1] = bx[q][1] + off;                   \
        oB[q][2] = bx[q][2] + off; oB[q][3] = bx[q][3] + off;                   \
        aR[q] = (oB[q][2] - oB[q][0]) * (oB[q][3] - oB[q][1]);                  \
        int slot = q * 1024 + tid;                                              \
        obm[0][slot] = oB[q][0]; obm[1][slot] = oB[q][1];                       \
        obm[2][slot] = oB[q][2]; obm[3][slot] = oB[q][3];                       \
    }                                                                           \
    __syncthreads();                                                            \
    if (tid < 64) {                                                             \
        int c0 = clscnt[lane];                                                  \
        int c1 = (lane < NCLS - 64) ? clscnt[64 + lane] : 0;                    \
        int p0 = c0;                                                            \
        for (int d = 1; d < 64; d <<= 1) { int o = __shfl_up(p0, d, 64); if (lane >= d) p0 += o; } \
        int tot0 = __shfl(p0, 63, 64);                                          \
        int p1 = c1;                                                            \
        for (int d = 1; d < 64; d <<= 1) { int o = __shfl_up(p1, d, 64); if (lane >= d) p1 += o; } \
        clsbase[lane] = p0 - c0;                                                \
        if (lane < NCLS - 64) clsbase[64 + lane] = tot0 + p1 - c1;              \
        if (lane == 63) clsbase[NCLS] = tot0 + __shfl(p1, NCLS - 64 - 1, 64);   \
    }                                                                           \
    __syncthreads();                                                            \
    if (tid < NCLS) {                                                           \
        int running = clsbase[tid];                                             \
        for (int ch = 0; ch < 32; ++ch) {                                       \
            u32 t = chunkcnt[ch][tid];                                          \
            chunkcnt[ch][tid] = (u32)running;                                   \
            running += (int)t;                                                  \
        }                                                                       \
    }                                                                           \
    __syncthreads();                                                            \
    _Pragma("unroll")                                                           \
    for (int q = 0; q < 2; ++q) {                                               \
        int cl = val[q] ? lab[q] : -1;                                          \
        int rank = 0;                                                           \
        for (int d = 1; d < 64; ++d) {                                          \
            int oc = __shfl_up(cl, d, 64);                                      \
            if (lane >= d && oc == cl) ++rank;                                  \
        }                                                                       \
        if (val[q]) {                                                           \
            int slot = q * 1024 + tid;                                          \
            seg[chunkcnt[slot >> 6][cl] + rank] = (u16)slot;                    \
        }                                                                       \
    }                                                                           \
    __syncthreads();

// ---- Pass 4b: SLIM per-class greedy at grid (B,5): no front half. One class
// per wave; boxes gathered from boxg via segg/permg, offset by offbg*c.
// Decision math verbatim; clears keptg; all-pairs adjacent-class cert -> violg. ----
__global__ void __launch_bounds__(1024) k_greedy(const u16* __restrict__ segg,
        const int* __restrict__ clsbg, const double* __restrict__ offbg,
        const u16* __restrict__ permg, const double* __restrict__ boxg,
        u8* __restrict__ keptg, int* __restrict__ violg) {
    __shared__ u64 amw[16][32];
    int img = blockIdx.x;
    int lane = threadIdx.x & 63, wv = threadIdx.x >> 6;
    int c = blockIdx.y * 16 + wv;
    const int* cb_ = clsbg + img * 81;
    int cbase = cb_[c];
    int m = cb_[c + 1] - cbase;
    if (m <= 0) return;                        // wave-uniform; no block barriers
    double offb = offbg[img];
    double off = offb * (double)c;
    const u16* sg = segg + (size_t)img * 2048;
    const u16* pg = permg + (size_t)img * 2048;
    const double* BG = boxg + (size_t)img * CAP * 4;
    u8* kp = keptg + (size_t)img * 2048;

    if (m <= 64) {
        int s_l = (lane < m) ? (int)sg[cbase + lane] : -1;
        double e0 = 0, e1 = 0, e2 = 0, e3 = 0, ea = 0;
        if (s_l >= 0) {
            const double* bg = BG + (size_t)pg[s_l] * 4;
            e0 = bg[0] + off; e1 = bg[1] + off;
            e2 = bg[2] + off; e3 = bg[3] + off;
            ea = (e2 - e0) * (e3 - e1);
        }
        if (m > 1) {
            u64 ovl = 0ULL;
            for (int k = 0; k < m; ++k) {
                double k0 = __shfl(e0, k, 64), k1 = __shfl(e1, k, 64);
                double k2 = __shfl(e2, k, 64), k3 = __shfl(e3, k, 64);
                double ka = __shfl(ea, k, 64);
                double ww = fmax(fmin(k2, e2) - fmax(k0, e0), 0.0);
                double hh = fmax(fmin(k3, e3) - fmax(k1, e1), 0.0);
                double inter = ww * hh;
                bool o = (lane > k) && (lane < m) &&
                         (inter > 0.45 * (ka + ea - inter + 1e-7));
                ovl |= o ? (1ULL << k) : 0ULL;
            }
            u64 live = (m >= 64) ? ~0ULL : ((1ULL << m) - 1ULL);
            for (int k = 0; k < m; ++k) {
                u64 kill = __ballot((ovl >> k) & 1ULL);
                if ((live >> k) & 1ULL) live &= ~kill;
            }
            if (s_l >= 0 && !((live >> lane) & 1ULL)) kp[s_l] = 0;
        }
        // all-pairs cert vs adjacent classes (f32, 0.4485 conservative)
        bool bad = false;
        if (s_l >= 0) {
            float c0 = (float)e0, c1 = (float)e1, c2v = (float)e2, c3 = (float)e3;
            float ca = (c2v - c0) * (c3 - c1);
            #pragma unroll
            for (int dd = 0; dd < 2; ++dd) {
                int cc = c + (dd ? 1 : -1);
                if (cc < 0 || cc >= NCLS) continue;
                double offc = offb * (double)cc;
                int je = cb_[cc + 1];
                for (int j = cb_[cc]; j < je; ++j) {
                    int t = (int)sg[j];
                    if (t > s_l) {
                        const double* bgt = BG + (size_t)pg[t] * 4;
                        float b0 = (float)(bgt[0] + offc), b1 = (float)(bgt[1] + offc);
                        float b2 = (float)(bgt[2] + offc), b3 = (float)(bgt[3] + offc);
                        float ww = fmaxf(fminf(c2v, b2) - fmaxf(c0, b0), 0.f);
                        float hh = fmaxf(fminf(c3, b3) - fmaxf(c1, b1), 0.f);
                        float inter = ww * hh;
                        float aj = (b2 - b0) * (b3 - b1);
                        if (inter > 0.4485f * (ca + aj - inter + 1e-7f)) bad = true;
                    }
                }
            }
        }
        if (__ballot(bad)) { if (lane == 0) atomicOr(&violg[img], 1); }
    } else {
        // cold: m > 64 — per-wave LDS bitmask greedy over global boxes
        u64* AM = amw[wv];
        if (lane < 32) {
            int lo = lane * 64;
            AM[lane] = (m >= lo + 64) ? ~0ULL : (m > lo ? ((1ULL << (m - lo)) - 1ULL) : 0ULL);
        }
        for (int k = 0; k < m; ++k) {
            if (!((AM[k >> 6] >> (k & 63)) & 1ULL)) continue;
            int sk = (int)sg[cbase + k];
            const double* bgk = BG + (size_t)pg[sk] * 4;
            double k0 = bgk[0] + off, k1 = bgk[1] + off;
            double k2 = bgk[2] + off, k3 = bgk[3] + off;
            double ka = (k2 - k0) * (k3 - k1);
            for (int j = k + 1 + lane; j < m; j += 64) {
                if (!((AM[j >> 6] >> (j & 63)) & 1ULL)) continue;
                int t = (int)sg[cbase + j];
                const double* bgt = BG + (size_t)pg[t] * 4;
                double b0 = bgt[0] + off, b1 = bgt[1] + off;
                double b2 = bgt[2] + off, b3 = bgt[3] + off;
                double ww = fmax(fmin(k2, b2) - fmax(k0, b0), 0.0);
                double hh = fmax(fmin(k3, b3) - fmax(k1, b1), 0.0);
                double inter = ww * hh;
                double aj = (b2 - b0) * (b3 - b1);
                if (inter > 0.45 * (ka + aj - inter + 1e-7))
                    atomicAnd(&AM[j >> 6], ~(1ULL << (j & 63)));
            }
        }
        for (int j = lane; j < m; j += 64)
            if (!((AM[j >> 6] >> (j & 63)) & 1ULL)) kp[(int)sg[cbase + j]] = 0;
        // cert (cold)
        bool bad = false;
        for (int ii = cbase + lane; ii < cbase + m; ii += 64) {
            int s = (int)sg[ii];
            const double* bgs = BG + (size_t)pg[s] * 4;
            float c0 = (float)(bgs[0] + off), c1 = (float)(bgs[1] + off);
            float c2v = (float)(bgs[2] + off), c3 = (float)(bgs[3] + off);
            float ca = (c2v - c0) * (c3 - c1);
            #pragma unroll
            for (int dd = 0; dd < 2; ++dd) {
                int cc = c + (dd ? 1 : -1);
                if (cc < 0 || cc >= NCLS) continue;
                double offc = offb * (double)cc;
                int je = cb_[cc + 1];
                for (int j = cb_[cc]; j < je; ++j) {
                    int t = (int)sg[j];
                    if (t > s) {
                        const double* bgt = BG + (size_t)pg[t] * 4;
                        float b0 = (float)(bgt[0] + offc), b1 = (float)(bgt[1] + offc);
                        float b2 = (float)(bgt[2] + offc), b3 = (float)(bgt[3] + offc);
                        float ww = fmaxf(fminf(c2v, b2) - fmaxf(c0, b0), 0.f);
                        float hh = fmaxf(fminf(c3, b3) - fmaxf(c1, b1), 0.f);
                        float inter = ww * hh;
                        float aj = (b2 - b0) * (b3 - b1);
                        if (inter > 0.4485f * (ca + aj - inter + 1e-7f)) bad = true;
                    }
                }
            }
        }
        if (__ballot(bad)) { if (lane == 0) atomicOr(&violg[img], 1); }
    }
}

// ---- Pass 4c: finish. Warm path: ballot keptg, rank, emit. Cold path:
// full front-half reconstruction + exact sequential greedy. ----
__global__ void __launch_bounds__(1024) k_fin(const u64* __restrict__ sb, const u32* __restrict__ si,
        const u16* __restrict__ permg, const double* __restrict__ boxg,
        const u8* __restrict__ keptg, const int* __restrict__ violg, float* __restrict__ out) {
    __shared__ double obm[4][K];
    __shared__ u16 labs[K];
    __shared__ u16 seg[K];
    __shared__ u32 chunkcnt[32][NCLS];
    __shared__ int clsbase[NCLS + 1];
    __shared__ int clscnt[NCLS];
    __shared__ double red[16], red2[16];
    __shared__ double s_offb;
    __shared__ int s_viol2;
    __shared__ u64 mask[32];
    __shared__ int wpfx[33];

    int img = blockIdx.x;
    int tid = threadIdx.x;
    int lane = tid & 63, wv = tid >> 6;
    const u64* A = sb + (size_t)img * CAP;
    const u32* I = si + (size_t)img * CAP;

    float* bo  = out + (size_t)img * DET * 4;
    float* so_ = out + (size_t)B * DET * 4 + (size_t)img * DET;
    float* lo  = out + (size_t)B * DET * 5 + (size_t)img * DET;

    if (violg[img] == 0) {
        // ---- WARM PATH ----
        u64 s0 = A[tid], s1 = A[1024 + tid];
        u32 f0 = I[tid], f1 = I[1024 + tid];
        const u8* kp = keptg + (size_t)img * 2048;
        bool k0 = (s0 != 0ULL) && (kp[tid] != 0);
        bool k1 = (s1 != 0ULL) && (kp[1024 + tid] != 0);
        u64 m0 = __ballot(k0), m1 = __ballot(k1);
        if (lane == 0) { mask[wv] = m0; mask[16 + wv] = m1; }
        __syncthreads();
        if (tid == 0) {
            int s = 0;
            for (int w2 = 0; w2 < 32; ++w2) { wpfx[w2] = s; s += __popcll(mask[w2]); }
            wpfx[32] = s;
        }
        __syncthreads();
        int total = wpfx[32]; if (total > DET) total = DET;
        #pragma unroll
        for (int q = 0; q < 2; ++q) {
            int slot = q * 1024 + tid;
            int w = slot >> 6, bpos = slot & 63;
            if ((mask[w] >> bpos) & 1ULL) {
                int r = wpfx[w] + __popcll(mask[w] & ((1ULL << bpos) - 1ULL));
                if (r < DET) {
                    int p = (int)permg[(size_t)img * 2048 + slot];
                    const double* bg = boxg + ((size_t)img * CAP + p) * 4;
                    bo[r * 4 + 0] = (float)bg[0]; bo[r * 4 + 1] = (float)bg[1];
                    bo[r * 4 + 2] = (float)bg[2]; bo[r * 4 + 3] = (float)bg[3];
                    u64 sv_ = q ? s1 : s0;
                    u32 fi_ = q ? f1 : f0;
                    so_[r] = (float)__longlong_as_double((long long)sv_);
                    lo[r] = (float)(fi_ % NCLS);
                }
            }
        }
        if (tid >= total && tid < DET) {
            bo[tid * 4 + 0] = 0.f; bo[tid * 4 + 1] = 0.f;
            bo[tid * 4 + 2] = 0.f; bo[tid * 4 + 3] = 0.f;
            so_[tid] = -1.0f; lo[tid] = -1.0f;
        }
        return;
    }

    // ---- COLD PATH: full reconstruction + exact sequential greedy ----
    NMS_FRONT_HALF

    {
        u64 v0 = __ballot(val[0]), v1 = __ballot(val[1]);
        if (lane == 0) { mask[wv] = v0; mask[16 + wv] = v1; }
    }
    bool alive[2]; alive[0] = val[0]; alive[1] = val[1];
    __syncthreads();
    int i = -1, kc = 0;
    while (true) {
        int start = i + 1;
        if (start >= K) break;
        int w = start >> 6;
        u64 m = mask[w] & (~0ULL << (start & 63));
        while (m == 0ULL) { if (++w >= 32) break; m = mask[w]; }
        if (w >= 32) break;
        i = (w << 6) + __ffsll((long long)m) - 1;
        ++kc;
        if (kc >= DET) break;
        double bi0 = obm[0][i], bi1 = obm[1][i];
        double bi2 = obm[2][i], bi3 = obm[3][i];
        double ai = (bi2 - bi0) * (bi3 - bi1);
        #pragma unroll
        for (int q = 0; q < 2; ++q) {
            int slot = q * 1024 + tid;
            double w_ = fmax(fmin(bi2, oB[q][2]) - fmax(bi0, oB[q][0]), 0.0);
            double h_ = fmax(fmin(bi3, oB[q][3]) - fmax(bi1, oB[q][1]), 0.0);
            double inter = w_ * h_;
            bool sup = inter > 0.45 * (ai + aR[q] - inter + 1e-7);
            if (alive[q] && slot > i && sup) {
                alive[q] = false;
                atomicAnd(&mask[slot >> 6], ~(1ULL << (slot & 63)));
            }
        }
        __syncthreads();
    }
    __syncthreads();

    if (tid == 0) {
        int s = 0;
        for (int w2 = 0; w2 < 32; ++w2) { wpfx[w2] = s; s += __popcll(mask[w2]); }
        wpfx[32] = s;
    }
    __syncthreads();
    int total = wpfx[32]; if (total > DET) total = DET;

    #pragma unroll
    for (int q = 0; q < 2; ++q) {
        int slot = q * 1024 + tid;
        int w = slot >> 6, bpos = slot & 63;
        if ((mask[w] >> bpos) & 1ULL) {
            int r = wpfx[w] + __popcll(mask[w] & ((1ULL << bpos) - 1ULL));
            if (r < DET) {
                bo[r * 4 + 0] = (float)bx[q][0]; bo[r * 4 + 1] = (float)bx[q][1];
                bo[r * 4 + 2] = (float)bx[q][2]; bo[r * 4 + 3] = (float)bx[q][3];
                so_[r] = (float)__longlong_as_double((long long)sv[q]);
                lo[r] = (float)lab[q];
            }
        }
    }
    if (tid >= total && tid < DET) {
        bo[tid * 4 + 0] = 0.f; bo[tid * 4 + 1] = 0.f;
        bo[tid * 4 + 2] = 0.f; bo[tid * 4 + 3] = 0.f;
        so_[tid] = -1.0f; lo[tid] = -1.0f;
    }
}

extern "C" void kernel_launch(void* const* d_in, const int* in_sizes, int n_in,
                              void* d_out, int out_size, void* d_ws, size_t ws_size,
                              hipStream_t stream) {
    const float* head = (const float*)d_in[0];   // [16,25200,85]
    const float* grid = (const float*)d_in[1];   // [25200,2]
    const float* ag   = (const float*)d_in[2];   // [25200,2]
    const float* stv  = (const float*)d_in[3];   // [25200,1]
    float* out = (float*)d_out;
    char* ws = (char*)d_ws;

    u64* sb     = (u64*)(ws + 0);                // 524288
    u32* si     = (u32*)(ws + 524288);           // 262144
    int* alist  = (int*)(ws + 786432);           // 262144 (dead after k_pairs)
    u16* permg  = (u16*)(ws + 786432);           // 65536  (alias alist)
    u8*  keptg  = (u8*)(ws + 851968);            // 32768  (alias alist)
    int* violg  = (int*)(ws + 884736);           // 64     (alias alist)
    u16* segg   = (u16*)(ws + 917504);           // 65536  (alias alist)
    int* clsbg  = (int*)(ws + 983040);           // 5184   (alias alist)
    double* offbg = (double*)(ws + 988288);      // 128    (alias alist; 8B aligned)
    u32* cnt    = (u32*)(ws + 1048576);          // 64
    u32* cntA   = (u32*)(ws + 1048640);          // 64
    u64* cut    = (u64*)(ws + 1048704);          // 128
    u16* smax16 = (u16*)(ws + 1048832);          // 806400 -> 1855232
    int* hist   = (int*)(ws + 1855232);          // 131072 -> 1986304
    u32* phist  = (u32*)(ws + 1986304);          // B*hblk*2048*4 (dead after k_redsum)
    double* boxg = (double*)(ws + 1986304);      // 2 MB, alias phist; written by k_pairs

    int hblk = 16;
    if (ws_size >= (size_t)1986304 + (size_t)B * 128 * 2048 * 4) hblk = 128;
    else if (ws_size >= (size_t)1986304 + (size_t)B * 64 * 2048 * 4) hblk = 64;

    k_hist   <<<dim3(hblk, B), 256, 0, stream>>>(head, phist, smax16);
    k_redsum <<<dim3(B, 8), 256, 0, stream>>>(phist, hist, hblk, cnt, cntA);
    k_cut    <<<1, 1024, 0, stream>>>(hist, cut);
    k_screen <<<dim3((NA + 255) / 256, B), 256, 0, stream>>>(smax16, cut, cntA, alist);
    k_pairs  <<<dim3(PBLK, B), 256, 0, stream>>>(head, cut, grid, ag, stv, cntA, alist, cnt, sb, si, boxg);
    k_sortp  <<<B, 1024, 0, stream>>>(cnt, sb, si, permg, keptg, violg, boxg, segg, clsbg, offbg);
    k_greedy <<<dim3(B, 5), 1024, 0, stream>>>(segg, clsbg, offbg, permg, boxg, keptg, violg);
    k_fin    <<<B, 1024, 0, stream>>>(sb, si, permg, boxg, keptg, violg, out);
}

// Round 24
// 154.843 us; speedup vs baseline: 1.0814x; 1.0814x over previous
//
#include <hip/hip_runtime.h>
#include <hip/hip_bf16.h>

#define B    16
#define NA   25200
#define NCH  85
#define NCLS 80
#define K    2048
#define CAP  4096
#define ACAP 4096
#define DET  300
#define TILE 64
#define NTILES 394                     // ceil(25200/64)
#define PBLK 64                        // k_pairs blocks per image
#define LBUF 2304                      // k_pairs LDS buffer
#define SBASE  0x3FD0000000000000ULL   // bits of 0.25 (double)
#define SSHIFT 42                      // -> 2048 bins over (0.25, 1.0)

typedef unsigned long long u64;
typedef unsigned int u32;
typedef unsigned short u16;
typedef unsigned char u8;

__device__ __forceinline__ double dsig(float x) { return 1.0 / (1.0 + exp(-(double)x)); }
__device__ __forceinline__ float  fsig(float x) { return 1.0f / (1.0f + __expf(-x)); }

// ---- Pass 1: full sweep with register-prefetch double buffering. ----
__global__ void __launch_bounds__(256) k_hist(const float* __restrict__ head,
                                              u32* __restrict__ phist, u16* __restrict__ smax16) {
    __shared__ float rows[TILE * NCH];
    __shared__ int h[2048];
    __shared__ float smaxT[TILE][4];
    int tid = threadIdx.x;
    int hblk = gridDim.x;
    for (int i = tid; i < 2048; i += 256) h[i] = 0;
    int img = blockIdx.y;
    const float* ibase = head + (size_t)img * NA * NCH;

    float4 pf[6];
    int tile = blockIdx.x;
    {
        int a0 = tile * TILE;
        int na = NA - a0; if (na > TILE) na = TILE;
        int nf4 = (na * NCH) >> 2;
        const float4* src = (const float4*)(ibase + (size_t)a0 * NCH);
        #pragma unroll
        for (int u = 0; u < 6; ++u) { int i = tid + u * 256; pf[u] = (i < nf4) ? src[i] : make_float4(0.f,0.f,0.f,0.f); }
    }
    for (; tile < NTILES; tile += hblk) {
        int a0 = tile * TILE;
        int na = NA - a0; if (na > TILE) na = TILE;
        int nf4 = (na * NCH) >> 2;
        __syncthreads();
        #pragma unroll
        for (int u = 0; u < 6; ++u) { int i = tid + u * 256; if (i < nf4) ((float4*)rows)[i] = pf[u]; }
        __syncthreads();
        int nt = tile + hblk;
        if (nt < NTILES) {
            int a0n = nt * TILE;
            int nan_ = NA - a0n; if (nan_ > TILE) nan_ = TILE;
            int nf4n = (nan_ * NCH) >> 2;
            const float4* srcn = (const float4*)(ibase + (size_t)a0n * NCH);
            #pragma unroll
            for (int u = 0; u < 6; ++u) { int i = tid + u * 256; pf[u] = (i < nf4n) ? srcn[i] : make_float4(0.f,0.f,0.f,0.f); }
        }
        for (int t = tid; t < 4 * na; t += 256) {
            int a = t >> 2, q = t & 3;
            float fo = fsig(rows[a * NCH + 4]);
            float lm = 0.0f;
            if (fo > 0.25f) {
                float qq = 0.24975f / fo;
                float cth = __logf(qq) - __logf(1.0f - qq);
                int c0 = q * 20;
                for (int c = c0; c < c0 + 20; ++c) {
                    float cl = rows[a * NCH + 5 + c];
                    if (cl > cth) {
                        float sc = fo * fsig(cl);
                        lm = fmaxf(lm, sc);
                        if (sc > 0.25f) {
                            u64 bits = (u64)__double_as_longlong((double)sc);
                            int bb = (int)((bits - SBASE) >> SSHIFT);
                            if (bb > 2047) bb = 2047;
                            atomicAdd(&h[bb], 1);
                        }
                    }
                }
            }
            smaxT[a][q] = lm;
        }
        __syncthreads();
        for (int t = tid; t < na; t += 256) {
            float m = fmaxf(fmaxf(smaxT[t][0], smaxT[t][1]), fmaxf(smaxT[t][2], smaxT[t][3]));
            u32 mb = __float_as_uint(m);
            smax16[(size_t)img * NA + a0 + t] = (u16)((mb + 0xFFFFu) >> 16);  // round UP
        }
    }
    __syncthreads();
    u32* dst = phist + ((size_t)img * hblk + blockIdx.x) * 2048;
    for (int i = tid; i < 2048; i += 256) dst[i] = (u32)h[i];
}

// ---- Pass 2a: parallel partial-histogram reduce (+ cnt/cntA zeroing) ----
__global__ void __launch_bounds__(256) k_redsum(const u32* __restrict__ phist,
                                                int* __restrict__ hist, int hblk,
                                                u32* __restrict__ cnt, u32* __restrict__ cntA) {
    int img = blockIdx.x;
    int bin = blockIdx.y * 256 + threadIdx.x;
    if (blockIdx.y == 0 && threadIdx.x == 0) cnt[img] = 0;
    if (blockIdx.y == 0 && threadIdx.x == 1) cntA[img] = 0;
    const u32* base = phist + (size_t)img * hblk * 2048 + bin;
    u32 s = 0;
    int p = 0;
    for (; p + 4 <= hblk; p += 4) {
        u32 a0 = base[(size_t)(p + 0) * 2048];
        u32 a1 = base[(size_t)(p + 1) * 2048];
        u32 a2 = base[(size_t)(p + 2) * 2048];
        u32 a3 = base[(size_t)(p + 3) * 2048];
        s += a0 + a1 + a2 + a3;
    }
    for (; p < hblk; ++p) s += base[(size_t)p * 2048];
    hist[img * 2048 + bin] = (int)s;
}

// ---- Pass 2b: cut-bin search, one wave per image ----
__global__ void __launch_bounds__(1024) k_cut(const int* __restrict__ hist, u64* __restrict__ cut) {
    int lane = threadIdx.x & 63;
    int img  = threadIdx.x >> 6;
    const int* h = hist + img * 2048;
    int v[32];
    #pragma unroll
    for (int ch = 0; ch < 32; ++ch) v[ch] = h[2047 - ch * 64 - lane];
    int cum = 0; u64 cb = 0;
    #pragma unroll
    for (int ch = 0; ch < 32; ++ch) {
        int pfx = v[ch];
        for (int d = 1; d < 64; d <<= 1) { int o = __shfl_up(pfx, d, 64); if (lane >= d) pfx += o; }
        u64 ball = __ballot(cum + pfx >= K);
        if (ball) {
            int fl = __ffsll((long long)ball) - 1;
            int bin = 2047 - ch * 64 - fl;
            cb = (bin >= 1) ? (SBASE + ((u64)(bin - 1) << SSHIFT)) : 0ULL;
            break;
        }
        cum += __shfl(pfx, 63, 64);
    }
    if (lane == 0) cut[img] = cb;
}

// ---- Pass 3a: screen anchors by smax upper bound ----
__global__ void __launch_bounds__(256) k_screen(const u16* __restrict__ smax16, const u64* __restrict__ cut,
                                                u32* __restrict__ cntA, int* __restrict__ alist) {
    __shared__ int lcnt, lbase, buf[256];
    int img = blockIdx.y;
    int a = blockIdx.x * 256 + threadIdx.x;
    if (threadIdx.x == 0) lcnt = 0;
    __syncthreads();
    u64 cutb = cut[img];
    float cutf = cutb ? (float)__longlong_as_double((long long)cutb) : 0.25f;
    float pre = fmaxf(0.2489f, cutf * 0.999f);
    if (a < NA) {
        float fup = __uint_as_float(((u32)smax16[(size_t)img * NA + a]) << 16);
        if (fup >= pre) buf[atomicAdd(&lcnt, 1)] = a;
    }
    __syncthreads();
    if (threadIdx.x == 0 && lcnt) lbase = atomicAdd(&cntA[img], (u32)lcnt);
    __syncthreads();
    for (int i = threadIdx.x; i < lcnt; i += 256) {
        int pos = lbase + i;
        if (pos < ACAP) alist[img * ACAP + pos] = buf[i];
    }
}

// ---- Pass 3b: pairs with per-block LDS compaction + f64 box decode at flush ----
__global__ void __launch_bounds__(256) k_pairs(const float* __restrict__ head, const u64* __restrict__ cut,
                                               const float* __restrict__ grid, const float* __restrict__ ag,
                                               const float* __restrict__ stv,
                                               const u32* __restrict__ cntA, const int* __restrict__ alist,
                                               u32* __restrict__ cnt, u64* __restrict__ sb, u32* __restrict__ si,
                                               double* __restrict__ boxg) {
    __shared__ u64 lsb[LBUF];
    __shared__ u32 lsi[LBUF];
    __shared__ u32 lcnt, lbase;
    int img = blockIdx.y;
    int tid = threadIdx.x;
    u64 cutb = cut[img];
    float cutf = cutb ? (float)__longlong_as_double((long long)cutb) : 0.25f;
    float pre = fmaxf(0.2489f, cutf * 0.999f);
    int nsur = (int)cntA[img]; if (nsur > ACAP) nsur = ACAP;
    int npairs = nsur * NCLS;
    u64* sbi = sb + (size_t)img * CAP;
    u32* sii = si + (size_t)img * CAP;
    const float* ibase = head + (size_t)img * NA * NCH;
    if (tid == 0) lcnt = 0;
    __syncthreads();

    int base = blockIdx.x * 256;
    int ntrip = (npairs > base) ? (npairs - base + PBLK * 256 - 1) / (PBLK * 256) : 0;
    for (int t = 0; t <= ntrip; ++t) {          // extra trip = final flush
        if (t < ntrip) {
            int p = base + tid + t * PBLK * 256;
            if (p < npairs) {
                int ai = (int)((u32)p / NCLS);
                int c  = p - ai * NCLS;
                int a  = alist[img * ACAP + ai];
                const float* row = ibase + (size_t)a * NCH;
                float o = row[4], cl = row[5 + c];
                float s32 = fsig(o) * fsig(cl);
                if (s32 >= pre) {
                    double sc = dsig(o) * dsig(cl);        // exact f64 decision
                    if (sc > 0.25) {
                        u64 bits = (u64)__double_as_longlong(sc);
                        if (bits >= cutb) {
                            u32 pos = atomicAdd(&lcnt, 1u);
                            if (pos < LBUF) { lsb[pos] = bits; lsi[pos] = (u32)(a * NCLS + c); }
                        }
                    }
                }
            }
        }
        __syncthreads();
        bool last = (t == ntrip);
        if ((!last && lcnt >= 2048) || (last && lcnt > 0)) {
            u32 n = lcnt; if (n > LBUF) n = LBUF;
            if (tid == 0) lbase = atomicAdd(&cnt[img], n);
            __syncthreads();
            for (u32 i = tid; i < n; i += 256) {
                u32 pos = lbase + i;
                if (pos < CAP) {
                    u32 idx = lsi[i];
                    sbi[pos] = lsb[i]; sii[pos] = idx;
                    int a = (int)(idx / NCLS);
                    const float* row = ibase + (size_t)a * NCH;
                    double p0 = dsig(row[0]), p1 = dsig(row[1]), p2 = dsig(row[2]), p3 = dsig(row[3]);
                    double st = (double)stv[a];
                    double xc = (p0 * 2.0 - 0.5 + (double)grid[a * 2 + 0]) * st;
                    double yc = (p1 * 2.0 - 0.5 + (double)grid[a * 2 + 1]) * st;
                    double w = p2 * 2.0; w = (w * w) * (double)ag[a * 2 + 0];
                    double h = p3 * 2.0; h = (h * h) * (double)ag[a * 2 + 1];
                    double* bg = boxg + ((size_t)img * CAP + pos) * 4;
                    bg[0] = xc - w * 0.5; bg[1] = yc - h * 0.5;
                    bg[2] = xc + w * 0.5; bg[3] = yc + h * 0.5;
                }
            }
            __syncthreads();
            if (tid == 0) lcnt = 0;
            __syncthreads();
        }
    }
}

// ---- Pass 4a: counting sort; sorted -> sb/si[0..K); perm -> permg; kept=1 ----
__global__ void __launch_bounds__(1024) k_sortp(const u32* __restrict__ cntArr,
                                                u64* __restrict__ sb, u32* __restrict__ si,
                                                u16* __restrict__ permg, u8* __restrict__ keptg,
                                                int* __restrict__ violg) {
    __shared__ u64 TA[4096];
    __shared__ u32 TI[4096];
    __shared__ u16 TP[4096];
    __shared__ u32 h2[2048];
    __shared__ u32 cntb[2048];
    __shared__ u32 segtot[32];
    int img = blockIdx.x;
    int tid = threadIdx.x;
    int lane = tid & 63, wv = tid >> 6;
    u32* tmp = TI;

    u64* A = sb + (size_t)img * CAP;
    u32* I = si + (size_t)img * CAP;
    int cnt = (int)cntArr[img]; if (cnt > CAP) cnt = CAP;

    keptg[(size_t)img * 2048 + tid] = 1;
    keptg[(size_t)img * 2048 + 1024 + tid] = 1;
    if (tid == 0) violg[img] = 0;

    for (int b = tid; b < 2048; b += 1024) h2[b] = 0;
    __syncthreads();
    for (int e = tid; e < cnt; e += 1024) {
        u64 bits = A[e];
        int b = (int)((bits - SBASE) >> SSHIFT);
        b = b < 0 ? 0 : (b > 2047 ? 2047 : b);
        atomicAdd(&h2[b], 1u);
    }
    __syncthreads();
    for (int s = wv; s < 32; s += 16) {
        int r = s * 64 + lane;
        u32 v = h2[2047 - r];
        cntb[2047 - r] = v;
        u32 p = v;
        for (int d = 1; d < 64; d <<= 1) { u32 o = __shfl_up(p, d, 64); if (lane >= d) p += o; }
        if (lane == 63) segtot[s] = p;
        tmp[r] = p - v;
    }
    __syncthreads();
    if (tid < 32) {
        u32 v = segtot[tid], p = v;
        for (int d = 1; d < 32; d <<= 1) { u32 o = __shfl_up(p, d, 64); if (lane >= d) p += o; }
        segtot[tid] = p - v;
    }
    __syncthreads();
    for (int s = wv; s < 32; s += 16) {
        int r = s * 64 + lane;
        h2[2047 - r] = tmp[r] + segtot[s];
    }
    __syncthreads();
    for (int e = tid; e < 4096; e += 1024) if (e >= cnt) { TA[e] = 0ULL; TI[e] = 0xFFFFFFFFu; TP[e] = 0; }
    __syncthreads();
    for (int e = tid; e < cnt; e += 1024) {
        u64 bits = A[e]; u32 idx = I[e];
        int b = (int)((bits - SBASE) >> SSHIFT);
        b = b < 0 ? 0 : (b > 2047 ? 2047 : b);
        u32 slot = atomicAdd(&h2[b], 1u);
        if (slot < 4096u) { TA[slot] = bits; TI[slot] = idx; TP[slot] = (u16)e; }
    }
    __syncthreads();
    u64 rb[4]; u32 ri[4]; int rp[4]; u16 rq[4];
    #pragma unroll
    for (int s4 = 0; s4 < 4; ++s4) {
        int p = tid + s4 * 1024;
        rp[s4] = -1;
        if (p < cnt) {
            u64 kb = TA[p]; u32 ki = TI[p]; u16 kq = TP[p];
            int b = (int)((kb - SBASE) >> SSHIFT);
            b = b < 0 ? 0 : (b > 2047 ? 2047 : b);
            int en = (int)h2[b];
            int st = en - (int)cntb[b];
            int r = st;
            for (int j = st; j < en; ++j) {
                u64 b2 = TA[j]; u32 i2 = TI[j];
                if (b2 > kb || (b2 == kb && i2 < ki)) ++r;
            }
            rb[s4] = kb; ri[s4] = ki; rq[s4] = kq; rp[s4] = r;
        }
    }
    __syncthreads();
    #pragma unroll
    for (int s4 = 0; s4 < 4; ++s4)
        if (rp[s4] >= 0 && rp[s4] < 4096) { TA[rp[s4]] = rb[s4]; TI[rp[s4]] = ri[s4]; TP[rp[s4]] = rq[s4]; }
    __syncthreads();
    A[tid] = TA[tid];               I[tid] = TI[tid];
    A[1024 + tid] = TA[1024 + tid]; I[1024 + tid] = TI[1024 + tid];
    permg[(size_t)img * 2048 + tid]        = TP[tid];
    permg[(size_t)img * 2048 + 1024 + tid] = TP[1024 + tid];
}

// ==== shared front-half macro (verbatim r21) ====
#define NMS_FRONT_HALF                                                          \
    u64 sv[2]; u32 fidx[2];                                                     \
    sv[0] = A[tid];        fidx[0] = I[tid];                                    \
    sv[1] = A[1024 + tid]; fidx[1] = I[1024 + tid];                             \
    if (tid < NCLS) clscnt[tid] = 0;                                            \
    for (int i = tid; i < 32 * NCLS; i += 1024) ((u32*)chunkcnt)[i] = 0;        \
    double bx[2][4];                                                            \
    int lab[2];                                                                 \
    bool val[2];                                                                \
    double lmax = -1e300, lmin = 1e300;                                         \
    __syncthreads();                                                            \
    _Pragma("unroll")                                                           \
    for (int q = 0; q < 2; ++q) {                                               \
        int slot = q * 1024 + tid;                                              \
        val[q] = (sv[q] != 0ULL);                                               \
        bx[q][0] = bx[q][1] = bx[q][2] = bx[q][3] = 0.0;                        \
        lab[q] = 0;                                                             \
        if (val[q]) {                                                           \
            lab[q] = (int)(fidx[q] % NCLS);                                     \
            int p = (int)permg[(size_t)img * 2048 + slot];                      \
            const double* bg = boxg + ((size_t)img * CAP + p) * 4;              \
            bx[q][0] = bg[0]; bx[q][1] = bg[1];                                 \
            bx[q][2] = bg[2]; bx[q][3] = bg[3];                                 \
            lmax = fmax(lmax, fmax(fmax(bx[q][0], bx[q][1]), fmax(bx[q][2], bx[q][3]))); \
            lmin = fmin(lmin, fmin(fmin(bx[q][0], bx[q][1]), fmin(bx[q][2], bx[q][3]))); \
            atomicAdd(&clscnt[lab[q]], 1);                                      \
            atomicAdd(&chunkcnt[slot >> 6][lab[q]], 1u);                        \
        }                                                                       \
        labs[slot] = val[q] ? (u16)lab[q] : (u16)0xFFFF;                        \
    }                                                                           \
    for (int d = 1; d < 64; d <<= 1) {                                          \
        lmax = fmax(lmax, __shfl_xor(lmax, d, 64));                             \
        lmin = fmin(lmin, __shfl_xor(lmin, d, 64));                             \
    }                                                                           \
    if (lane == 0) { red[wv] = lmax; red2[wv] = lmin; }                         \
    __syncthreads();                                                            \
    if (tid == 0) {                                                             \
        double m = red[0], mn = red2[0];                                        \
        for (int w2 = 1; w2 < 16; ++w2) { m = fmax(m, red[w2]); mn = fmin(mn, red2[w2]); } \
        s_offb = m + 1.0;                                                       \
        s_viol2 = (m + 2.0 + mn < 0.0) ? 1 : 0;                                 \
    }                                                                           \
    __syncthreads();                                                            \
    double offb = s_offb;                                                       \
    double oB[2][4], aR[2];                                                     \
    _Pragma("unroll")                                                           \
    for (int q = 0; q < 2; ++q) {                                               \
        double off = offb * (double)lab[q];                                     \
        oB[q][0] = bx[q][0] + off; oB[q][1] = bx[q][1] + off;                   \
        oB[q][2] = bx[q][2] + off; oB[q][3] = bx[q][3] + off;                   \
        aR[q] = (oB[q][2] - oB[q][0]) * (oB[q][3] - oB[q][1]);                  \
        int slot = q * 1024 + tid;                                              \
        obm[0][slot] = oB[q][0]; obm[1][slot] = oB[q][1];                       \
        obm[2][slot] = oB[q][2]; obm[3][slot] = oB[q][3];                       \
    }                                                                           \
    __syncthreads();                                                            \
    if (tid < 64) {                                                             \
        int c0 = clscnt[lane];                                                  \
        int c1 = (lane < NCLS - 64) ? clscnt[64 + lane] : 0;                    \
        int p0 = c0;                                                            \
        for (int d = 1; d < 64; d <<= 1) { int o = __shfl_up(p0, d, 64); if (lane >= d) p0 += o; } \
        int tot0 = __shfl(p0, 63, 64);                                          \
        int p1 = c1;                                                            \
        for (int d = 1; d < 64; d <<= 1) { int o = __shfl_up(p1, d, 64); if (lane >= d) p1 += o; } \
        clsbase[lane] = p0 - c0;                                                \
        if (lane < NCLS - 64) clsbase[64 + lane] = tot0 + p1 - c1;              \
        if (lane == 63) clsbase[NCLS] = tot0 + __shfl(p1, NCLS - 64 - 1, 64);   \
    }                                                                           \
    __syncthreads();                                                            \
    if (tid < NCLS) {                                                           \
        int running = clsbase[tid];                                             \
        for (int ch = 0; ch < 32; ++ch) {                                       \
            u32 t = chunkcnt[ch][tid];                                          \
            chunkcnt[ch][tid] = (u32)running;                                   \
            running += (int)t;                                                  \
        }                                                                       \
    }                                                                           \
    __syncthreads();                                                            \
    _Pragma("unroll")                                                           \
    for (int q = 0; q < 2; ++q) {                                               \
        int cl = val[q] ? lab[q] : -1;                                          \
        int rank = 0;                                                           \
        for (int d = 1; d < 64; ++d) {                                          \
            int oc = __shfl_up(cl, d, 64);                                      \
            if (lane >= d && oc == cl) ++rank;                                  \
        }                                                                       \
        if (val[q]) {                                                           \
            int slot = q * 1024 + tid;                                          \
            seg[chunkcnt[slot >> 6][cl] + rank] = (u16)slot;                    \
        }                                                                       \
    }                                                                           \
    __syncthreads();

// ---- Pass 4b: per-class greedy at grid (B,5) + ALL-PAIRS adjacent-class cert
// (kept-independent, conservative superset of kept-based cert -> exactness
// preserved via k_fin's fallback). Clears keptg; sets violg. ----
__global__ void __launch_bounds__(1024) k_greedy(const u64* __restrict__ sb, const u32* __restrict__ si,
        const u16* __restrict__ permg, const double* __restrict__ boxg,
        u8* __restrict__ keptg, int* __restrict__ violg) {
    __shared__ double obm[4][K];
    __shared__ u16 labs[K];
    __shared__ u16 seg[K];
    __shared__ u32 chunkcnt[32][NCLS];
    __shared__ int clsbase[NCLS + 1];
    __shared__ int clscnt[NCLS];
    __shared__ double red[16], red2[16];
    __shared__ double s_offb;
    __shared__ int s_viol2;
    __shared__ u64 amw[16][32];

    int img = blockIdx.x;
    int tid = threadIdx.x;
    int lane = tid & 63, wv = tid >> 6;
    const u64* A = sb + (size_t)img * CAP;
    const u32* I = si + (size_t)img * CAP;

    NMS_FRONT_HALF

    if (tid == 0 && s_viol2) atomicOr(&violg[img], 1);

    // one class per wave: c = part*16 + wv
    int c = blockIdx.y * 16 + wv;
    int cbase = clsbase[c];
    int m = clsbase[c + 1] - cbase;
    u8* kp = keptg + (size_t)img * 2048;
    if (m > 1) {
        if (m <= 64) {
            int s_l = (lane < m) ? (int)seg[cbase + lane] : -1;
            double e0 = 0, e1 = 0, e2 = 0, e3 = 0, ea = 0;
            if (s_l >= 0) {
                e0 = obm[0][s_l]; e1 = obm[1][s_l];
                e2 = obm[2][s_l]; e3 = obm[3][s_l];
                ea = (e2 - e0) * (e3 - e1);
            }
            u64 ovl = 0ULL;
            for (int k = 0; k < m; ++k) {
                double k0 = __shfl(e0, k, 64), k1 = __shfl(e1, k, 64);
                double k2 = __shfl(e2, k, 64), k3 = __shfl(e3, k, 64);
                double ka = __shfl(ea, k, 64);
                double ww = fmax(fmin(k2, e2) - fmax(k0, e0), 0.0);
                double hh = fmax(fmin(k3, e3) - fmax(k1, e1), 0.0);
                double inter = ww * hh;
                bool o = (lane > k) && (lane < m) &&
                         (inter > 0.45 * (ka + ea - inter + 1e-7));
                ovl |= o ? (1ULL << k) : 0ULL;
            }
            u64 live = (m >= 64) ? ~0ULL : ((1ULL << m) - 1ULL);
            for (int k = 0; k < m; ++k) {
                u64 kill = __ballot((ovl >> k) & 1ULL);
                if ((live >> k) & 1ULL) live &= ~kill;
            }
            if (s_l >= 0 && !((live >> lane) & 1ULL)) kp[s_l] = 0;
        } else {
            u64* AM = amw[wv];
            if (lane < 32) {
                int lo = lane * 64;
                AM[lane] = (m >= lo + 64) ? ~0ULL : (m > lo ? ((1ULL << (m - lo)) - 1ULL) : 0ULL);
            }
            for (int k = 0; k < m; ++k) {
                if (!((AM[k >> 6] >> (k & 63)) & 1ULL)) continue;
                int sk = (int)seg[cbase + k];
                double k0 = obm[0][sk], k1 = obm[1][sk];
                double k2 = obm[2][sk], k3 = obm[3][sk];
                double ka = (k2 - k0) * (k3 - k1);
                for (int j = k + 1 + lane; j < m; j += 64) {
                    if (!((AM[j >> 6] >> (j & 63)) & 1ULL)) continue;
                    int t = (int)seg[cbase + j];
                    double b0 = obm[0][t], b1 = obm[1][t];
                    double b2 = obm[2][t], b3 = obm[3][t];
                    double ww = fmax(fmin(k2, b2) - fmax(k0, b0), 0.0);
                    double hh = fmax(fmin(k3, b3) - fmax(k1, b1), 0.0);
                    double inter = ww * hh;
                    double aj = (b2 - b0) * (b3 - b1);
                    if (inter > 0.45 * (ka + aj - inter + 1e-7))
                        atomicAnd(&AM[j >> 6], ~(1ULL << (j & 63)));
                }
            }
            for (int j = lane; j < m; j += 64)
                if (!((AM[j >> 6] >> (j & 63)) & 1ULL)) kp[(int)seg[cbase + j]] = 0;
        }
    }

    // ALL-PAIRS cert for class c vs adjacent classes (f32, 0.4485 conservative)
    {
        int cend = cbase + m;
        bool bad = false;
        for (int ii = cbase + lane; ii < cend; ii += 64) {
            int s = (int)seg[ii];
            float c0 = (float)obm[0][s], c1 = (float)obm[1][s];
            float c2v = (float)obm[2][s], c3 = (float)obm[3][s];
            float ca = (c2v - c0) * (c3 - c1);
            #pragma unroll
            for (int dd = 0; dd < 2; ++dd) {
                int cc = c + (dd ? 1 : -1);
                if (cc < 0 || cc >= NCLS) continue;
                int je = clsbase[cc + 1];
                for (int j = clsbase[cc]; j < je; ++j) {
                    int t = (int)seg[j];
                    if (t > s) {
                        float b0 = (float)obm[0][t], b1 = (float)obm[1][t];
                        float b2 = (float)obm[2][t], b3 = (float)obm[3][t];
                        float ww = fmaxf(fminf(c2v, b2) - fmaxf(c0, b0), 0.f);
                        float hh = fmaxf(fminf(c3, b3) - fmaxf(c1, b1), 0.f);
                        float inter = ww * hh;
                        float aj = (b2 - b0) * (b3 - b1);
                        if (inter > 0.4485f * (ca + aj - inter + 1e-7f)) bad = true;
                    }
                }
            }
        }
        if (__ballot(bad)) { if (lane == 0) atomicOr(&violg[img], 1); }
    }
}

// ---- Pass 4c: finish. Warm path (violg==0): no front half — ballot keptg,
// rank, emit from boxg via permg. Cold path: front half + exact fallback. ----
__global__ void __launch_bounds__(1024) k_fin(const u64* __restrict__ sb, const u32* __restrict__ si,
        const u16* __restrict__ permg, const double* __restrict__ boxg,
        const u8* __restrict__ keptg, const int* __restrict__ violg, float* __restrict__ out) {
    __shared__ double obm[4][K];
    __shared__ u16 labs[K];
    __shared__ u16 seg[K];
    __shared__ u32 chunkcnt[32][NCLS];
    __shared__ int clsbase[NCLS + 1];
    __shared__ int clscnt[NCLS];
    __shared__ double red[16], red2[16];
    __shared__ double s_offb;
    __shared__ int s_viol2;
    __shared__ u64 mask[32];
    __shared__ int wpfx[33];

    int img = blockIdx.x;
    int tid = threadIdx.x;
    int lane = tid & 63, wv = tid >> 6;
    const u64* A = sb + (size_t)img * CAP;
    const u32* I = si + (size_t)img * CAP;

    float* bo  = out + (size_t)img * DET * 4;
    float* so_ = out + (size_t)B * DET * 4 + (size_t)img * DET;
    float* lo  = out + (size_t)B * DET * 5 + (size_t)img * DET;

    if (violg[img] == 0) {
        // ---- WARM PATH: no LDS front half ----
        u64 s0 = A[tid], s1 = A[1024 + tid];
        u32 f0 = I[tid], f1 = I[1024 + tid];
        const u8* kp = keptg + (size_t)img * 2048;
        bool k0 = (s0 != 0ULL) && (kp[tid] != 0);
        bool k1 = (s1 != 0ULL) && (kp[1024 + tid] != 0);
        u64 m0 = __ballot(k0), m1 = __ballot(k1);
        if (lane == 0) { mask[wv] = m0; mask[16 + wv] = m1; }
        __syncthreads();
        if (tid == 0) {
            int s = 0;
            for (int w2 = 0; w2 < 32; ++w2) { wpfx[w2] = s; s += __popcll(mask[w2]); }
            wpfx[32] = s;
        }
        __syncthreads();
        int total = wpfx[32]; if (total > DET) total = DET;
        #pragma unroll
        for (int q = 0; q < 2; ++q) {
            int slot = q * 1024 + tid;
            int w = slot >> 6, bpos = slot & 63;
            if ((mask[w] >> bpos) & 1ULL) {
                int r = wpfx[w] + __popcll(mask[w] & ((1ULL << bpos) - 1ULL));
                if (r < DET) {
                    int p = (int)permg[(size_t)img * 2048 + slot];
                    const double* bg = boxg + ((size_t)img * CAP + p) * 4;
                    bo[r * 4 + 0] = (float)bg[0]; bo[r * 4 + 1] = (float)bg[1];
                    bo[r * 4 + 2] = (float)bg[2]; bo[r * 4 + 3] = (float)bg[3];
                    u64 sv_ = q ? s1 : s0;
                    u32 fi_ = q ? f1 : f0;
                    so_[r] = (float)__longlong_as_double((long long)sv_);
                    lo[r] = (float)(fi_ % NCLS);
                }
            }
        }
        if (tid >= total && tid < DET) {
            bo[tid * 4 + 0] = 0.f; bo[tid * 4 + 1] = 0.f;
            bo[tid * 4 + 2] = 0.f; bo[tid * 4 + 3] = 0.f;
            so_[tid] = -1.0f; lo[tid] = -1.0f;
        }
        return;
    }

    // ---- COLD PATH: full reconstruction + exact sequential greedy ----
    NMS_FRONT_HALF

    {
        u64 v0 = __ballot(val[0]), v1 = __ballot(val[1]);
        if (lane == 0) { mask[wv] = v0; mask[16 + wv] = v1; }
    }
    bool alive[2]; alive[0] = val[0]; alive[1] = val[1];
    __syncthreads();
    int i = -1, kc = 0;
    while (true) {
        int start = i + 1;
        if (start >= K) break;
        int w = start >> 6;
        u64 m = mask[w] & (~0ULL << (start & 63));
        while (m == 0ULL) { if (++w >= 32) break; m = mask[w]; }
        if (w >= 32) break;
        i = (w << 6) + __ffsll((long long)m) - 1;
        ++kc;
        if (kc >= DET) break;
        double bi0 = obm[0][i], bi1 = obm[1][i];
        double bi2 = obm[2][i], bi3 = obm[3][i];
        double ai = (bi2 - bi0) * (bi3 - bi1);
        #pragma unroll
        for (int q = 0; q < 2; ++q) {
            int slot = q * 1024 + tid;
            double w_ = fmax(fmin(bi2, oB[q][2]) - fmax(bi0, oB[q][0]), 0.0);
            double h_ = fmax(fmin(bi3, oB[q][3]) - fmax(bi1, oB[q][1]), 0.0);
            double inter = w_ * h_;
            bool sup = inter > 0.45 * (ai + aR[q] - inter + 1e-7);
            if (alive[q] && slot > i && sup) {
                alive[q] = false;
                atomicAnd(&mask[slot >> 6], ~(1ULL << (slot & 63)));
            }
        }
        __syncthreads();
    }
    __syncthreads();

    if (tid == 0) {
        int s = 0;
        for (int w2 = 0; w2 < 32; ++w2) { wpfx[w2] = s; s += __popcll(mask[w2]); }
        wpfx[32] = s;
    }
    __syncthreads();
    int total = wpfx[32]; if (total > DET) total = DET;

    #pragma unroll
    for (int q = 0; q < 2; ++q) {
        int slot = q * 1024 + tid;
        int w = slot >> 6, bpos = slot & 63;
        if ((mask[w] >> bpos) & 1ULL) {
            int r = wpfx[w] + __popcll(mask[w] & ((1ULL << bpos) - 1ULL));
            if (r < DET) {
                bo[r * 4 + 0] = (float)bx[q][0]; bo[r * 4 + 1] = (float)bx[q][1];
                bo[r * 4 + 2] = (float)bx[q][2]; bo[r * 4 + 3] = (float)bx[q][3];
                so_[r] = (float)__longlong_as_double((long long)sv[q]);
                lo[r] = (float)lab[q];
            }
        }
    }
    if (tid >= total && tid < DET) {
        bo[tid * 4 + 0] = 0.f; bo[tid * 4 + 1] = 0.f;
        bo[tid * 4 + 2] = 0.f; bo[tid * 4 + 3] = 0.f;
        so_[tid] = -1.0f; lo[tid] = -1.0f;
    }
}

extern "C" void kernel_launch(void* const* d_in, const int* in_sizes, int n_in,
                              void* d_out, int out_size, void* d_ws, size_t ws_size,
                              hipStream_t stream) {
    const float* head = (const float*)d_in[0];   // [16,25200,85]
    const float* grid = (const float*)d_in[1];   // [25200,2]
    const float* ag   = (const float*)d_in[2];   // [25200,2]
    const float* stv  = (const float*)d_in[3];   // [25200,1]
    float* out = (float*)d_out;
    char* ws = (char*)d_ws;

    u64* sb     = (u64*)(ws + 0);                // 524288
    u32* si     = (u32*)(ws + 524288);           // 262144
    int* alist  = (int*)(ws + 786432);           // 262144 (dead after k_pairs)
    u16* permg  = (u16*)(ws + 786432);           // 65536  (alias alist)
    u8*  keptg  = (u8*)(ws + 851968);            // 32768  (alias alist)
    int* violg  = (int*)(ws + 884736);           // 64     (alias alist)
    u32* cnt    = (u32*)(ws + 1048576);          // 64
    u32* cntA   = (u32*)(ws + 1048640);          // 64
    u64* cut    = (u64*)(ws + 1048704);          // 128
    u16* smax16 = (u16*)(ws + 1048832);          // 806400 -> 1855232
    int* hist   = (int*)(ws + 1855232);          // 131072 -> 1986304
    u32* phist  = (u32*)(ws + 1986304);          // B*hblk*2048*4 (dead after k_redsum)
    double* boxg = (double*)(ws + 1986304);      // 2 MB, alias phist; written by k_pairs

    int hblk = 16;
    if (ws_size >= (size_t)1986304 + (size_t)B * 128 * 2048 * 4) hblk = 128;
    else if (ws_size >= (size_t)1986304 + (size_t)B * 64 * 2048 * 4) hblk = 64;

    k_hist   <<<dim3(hblk, B), 256, 0, stream>>>(head, phist, smax16);
    k_redsum <<<dim3(B, 8), 256, 0, stream>>>(phist, hist, hblk, cnt, cntA);
    k_cut    <<<1, 1024, 0, stream>>>(hist, cut);
    k_screen <<<dim3((NA + 255) / 256, B), 256, 0, stream>>>(smax16, cut, cntA, alist);
    k_pairs  <<<dim3(PBLK, B), 256, 0, stream>>>(head, cut, grid, ag, stv, cntA, alist, cnt, sb, si, boxg);
    k_sortp  <<<B, 1024, 0, stream>>>(cnt, sb, si, permg, keptg, violg);
    k_greedy <<<dim3(B, 5), 1024, 0, stream>>>(sb, si, permg, boxg, keptg, violg);
    k_fin    <<<B, 1024, 0, stream>>>(sb, si, permg, boxg, keptg, violg, out);
}